// Round 14
// baseline (381.714 us; speedup 1.0000x reference)
//
#include <hip/hip_runtime.h>
#include <hip/hip_fp16.h>

typedef __half f16;
typedef _Float16 h8 __attribute__((ext_vector_type(8)));
typedef _Float16 h4 __attribute__((ext_vector_type(4)));
typedef _Float16 h2 __attribute__((ext_vector_type(2)));
typedef float f32x4 __attribute__((ext_vector_type(4)));

#define NN 255          // real nodes
#define BB 512          // batch
#define TSS 264         // T LDS row stride in f16

static __device__ __forceinline__ f16 f2h(float x) { return __float2half(x); }

union H8u { h8 v; h2 p[4]; };

// ======== panel layout: arr[row/16][KPB][16][8] — loads are 256B-contiguous per q-group,
// per-k-iter advance is 1KB (fits addressing-friendly strides) ========

// ========== setup1: convert W1..W4 to 16-row panel f16 (zeroing done by memsetAsync) ==========
__device__ __forceinline__ void conv_wt(const float* __restrict__ W, f16* __restrict__ Wtp,
                                        int K, int N, int KPB, int f, int tid) {
    int Kpad = KPB * 8;
    for (int k = tid; k < Kpad; k += 256) {
        float v = (f < N && k < K) ? W[(size_t)k * N + f] : 0.f;
        Wtp[((((size_t)(f >> 4) * KPB + (k >> 3)) * 16 + (f & 15)) << 3) + (k & 7)] = f2h(v);
    }
}

// grid = 320 + 128 + 320 + 448 = 1216
__global__ __launch_bounds__(256) void setup1(
        const float* W1, const float* W2, const float* W3, const float* W4,
        f16* Wt1, f16* Wt2, f16* Wt3, f16* Wt4) {
    int f = blockIdx.x, tid = threadIdx.x;
    if (f < 320) conv_wt(W1, Wt1, 400, 300, 52, f, tid);
    else if (f < 448) conv_wt(W2, Wt2, 300, 100, 40, f - 320, tid);
    else if (f < 768) conv_wt(W3, Wt3, 100, 300, 16, f - 448, tid);
    else conv_wt(W4, Wt4, 300, 400, 40, f - 768, tid);
}

// ========== setup2: scatter COO -> dense ==========
__global__ void setup2(const int* __restrict__ smi, const float* __restrict__ smv,
                       const int* __restrict__ spi, const float* __restrict__ spv,
                       float* __restrict__ dadsm, float* __restrict__ dadsp) {
    int t = blockIdx.x * 256 + threadIdx.x;
    if (blockIdx.x < 10) {
        if (t < 2550) atomicAdd(&dadsm[smi[2 * t] * 256 + smi[2 * t + 1]], smv[t]);
    } else {
        t -= 2560;
        if (t >= 0 && t < 2550) atomicAdd(&dadsp[spi[2 * t] * 256 + spi[2 * t + 1]], spv[t]);
    }
}

// ========== setup3: DAD panel f16 + rowsums + T0f = DADsm@H ==========
// grid = 512 + 128 + 32768 = 33408
__global__ __launch_bounds__(256) void setup3(
        const float* __restrict__ dadsm, f16* __restrict__ dadpsm,
        float* __restrict__ rsm, float* __restrict__ rsp,
        const float* __restrict__ H, float* __restrict__ T0f) {
    int bi = blockIdx.x, tid = threadIdx.x;
    if (bi < 512) {                        // convert both DADs (dadpsp contiguous after dadpsm)
        int i = bi * 256 + tid;
        int which = i >> 16, rc = i & 65535;
        int node = rc >> 8, k = rc & 255;
        float v = (node < NN) ? dadsm[(size_t)which * NN * 256 + rc] : 0.f;
        dadpsm[(size_t)which * 65536 +
               ((((node >> 4) * 32 + (k >> 3)) * 16 + (node & 15)) << 3) + (k & 7)] = f2h(v);
        return;
    }
    int lane = tid & 63;
    if (bi < 640) {                        // rowsums: 512..575 rsm, 576..639 rsp
        int which = (bi < 576) ? 0 : 1;
        int base = which ? 576 : 512;
        const float* dm = dadsm + (size_t)which * NN * 256;
        float* r = which ? rsp : rsm;
        int i = (bi - base) * 4 + (tid >> 6);
        float s = 0.f;
        if (i < NN) {
            f32x4 d = ((const f32x4*)(dm + (size_t)i * 256))[lane];
            s = d.x + d.y + d.z + d.w;
#pragma unroll
            for (int off = 1; off < 64; off <<= 1) s += __shfl_xor(s, off);
        }
        if (lane == 0 && i < 256) r[i] = (i < NN) ? s : 0.f;
        return;
    }
    // T0f[b][node][2] = (DADsm @ H): wave per (b,node)
    int gw = (bi - 640) * 4 + (tid >> 6);
    if (gw >= BB * 256) return;
    int b = gw >> 8, i = gw & 255;
    float a0 = 0.f, a1 = 0.f;
    if (i < NN) {
        f32x4 d = ((const f32x4*)(dadsm + (size_t)i * 256))[lane];
        const float2* yb2 = (const float2*)(H + (size_t)b * 510);
        float2 p0 = yb2[4 * lane], p1 = yb2[4 * lane + 1], p2 = yb2[4 * lane + 2];
        float2 p3 = (lane < 63) ? yb2[4 * lane + 3] : make_float2(0.f, 0.f);
        a0 = d.x * p0.x + d.y * p1.x + d.z * p2.x + d.w * p3.x;
        a1 = d.x * p0.y + d.y * p1.y + d.z * p2.y + d.w * p3.y;
#pragma unroll
        for (int off = 1; off < 64; off <<= 1) {
            a0 += __shfl_xor(a0, off);
            a1 += __shfl_xor(a1, off);
        }
    }
    if (lane == 0) {
        T0f[(size_t)gw * 2 + 0] = a0;
        T0f[(size_t)gw * 2 + 1] = a1;
    }
}

// ============ fused layer: Xn = relu( DAD @ (X@W + bias) ) ============
// All fragment sources in 16-row panel layout [row/16][KPB][16][8]. MODE 0: store f16
// panel layout. MODE 2 (L4): contract relu(acc2) with W5 in-register, atomicAdd into T5.
// R2 (L1): A-fragments generated in-register from the rank-2 L0 expansion.
template <int KPB, int CT, bool R2, int MODE>
__global__ __launch_bounds__(256, 4) void fused_layer(
        const f16* __restrict__ X,      // [b*16 + node/16][KPB][16][8] (unused if R2)
        const f16* __restrict__ Wtp,    // [feat/16][KPB][16][8]
        const float* __restrict__ bias, // [Nout] f32
        const f16* __restrict__ dadp,   // [nodeout/16][32][16][8]
        f16* __restrict__ Xn,           // MODE 0: panel layout, KPBn = SN>>3
        int Nout, int SN, int ntiles, int rev,
        const float* __restrict__ T0p,  // R2: [512][256][2] f32
        const float* __restrict__ rsmp, // R2: [256] f32
        const float* __restrict__ W0f,  // R2: [2][400] f32
        const float* __restrict__ b0f,  // R2: [400] f32
        const float* __restrict__ W5g,  // MODE 2: [400][2] f32
        float* __restrict__ T5) {       // MODE 2: [512][256][2] f32 (pre-zeroed)
    __shared__ _Float16 T[64 * TSS];
    __shared__ _Float16 WL[R2 ? 1344 : 4];
    const int id = blockIdx.x;
    int s = id >> 3;
    int bq = s / ntiles;
    const int tile = s - bq * ntiles;
    if (rev) bq = 63 - bq;
    const int b = ((id & 7) << 6) + bq;
    const int n0 = tile * 64;
    const int tid = threadIdx.x;
    const int w = tid >> 6;
    const int ln = tid & 15;
    const int q = (tid >> 4) & 3;

    // ---- R2 prologue ----
    h2 a0s[4], a1s[4], rvs[4];
    if constexpr (R2) {
        for (int i2 = tid; i2 < 448; i2 += 256) {
            WL[i2]       = (_Float16)(i2 < 400 ? W0f[i2] : 0.f);
            WL[448 + i2] = (_Float16)(i2 < 400 ? W0f[400 + i2] : 0.f);
            WL[896 + i2] = (_Float16)(i2 < 400 ? b0f[i2] : 0.f);
        }
#pragma unroll
        for (int t = 0; t < 4; t++) {
            int node = 64 * w + 16 * t + ln;
            const float* tp = T0p + ((size_t)b * 256 + node) * 2;
            _Float16 x0 = (_Float16)tp[0];
            _Float16 x1 = (_Float16)tp[1];
            _Float16 rv = (_Float16)rsmp[node];
            a0s[t] = (h2){x0, x0};
            a1s[t] = (h2){x1, x1};
            rvs[t] = (h2){rv, rv};
        }
        __syncthreads();
    }

    // ---- stage 1: wave w: nodes 64w..64w+63 (panels 4w..4w+3) x CT*16 feats ----
    f32x4 acc[4][CT];
#pragma unroll
    for (int t = 0; t < 4; t++)
#pragma unroll
        for (int c = 0; c < CT; c++) acc[t][c] = (f32x4){0.f, 0.f, 0.f, 0.f};

    const f16* xb = R2 ? (const f16*)nullptr : X + (size_t)b * KPB * 2048;
    const f16* wp = Wtp + (size_t)tile * KPB * 512;   // tile = 4 feat-panels

    h8 afr[2][4];
    if constexpr (!R2) {
#pragma unroll
        for (int t = 0; t < 4; t++)
            afr[0][t] = *(const h8*)(xb + ((((4 * w + t) * KPB + q) * 16 + ln) << 3));
    }

#pragma unroll
    for (int kb = 0; kb < KPB; kb += 4) {
        const int cur = (kb >> 2) & 1, nxt = cur ^ 1;
        h8 bf[CT];
#pragma unroll
        for (int c = 0; c < CT; c++)
            bf[c] = *(const h8*)(wp + (((c * KPB + kb + q) * 16 + ln) << 3));
        h8 afc[4];
        if constexpr (R2) {
            H8u wa, wb, bl;
            wa.v = *(const h8*)&WL[(kb + q) * 8];
            wb.v = *(const h8*)&WL[448 + (kb + q) * 8];
            bl.v = *(const h8*)&WL[896 + (kb + q) * 8];
            const h2 z2 = (h2){(_Float16)0.f, (_Float16)0.f};
#pragma unroll
            for (int t = 0; t < 4; t++) {
                H8u r;
#pragma unroll
                for (int j = 0; j < 4; j++)
                    r.p[j] = __builtin_elementwise_max(
                        a0s[t] * wa.p[j] + a1s[t] * wb.p[j] + rvs[t] * bl.p[j], z2);
                afc[t] = r.v;
            }
        } else {
            if (kb + 4 < KPB) {
#pragma unroll
                for (int t = 0; t < 4; t++)
                    afr[nxt][t] = *(const h8*)(xb + ((((4 * w + t) * KPB + kb + 4 + q) * 16 + ln) << 3));
            }
#pragma unroll
            for (int t = 0; t < 4; t++) afc[t] = afr[cur][t];
        }
#pragma unroll
        for (int c = 0; c < CT; c++)
#pragma unroll
            for (int t = 0; t < 4; t++)
                acc[t][c] = __builtin_amdgcn_mfma_f32_16x16x32_f16(afc[t], bf[c], acc[t][c], 0, 0, 0);
    }

    // bias + pack to T[feat][node]
#pragma unroll
    for (int c = 0; c < CT; c++) {
        int fl = 16 * c + ln;
        int gf = n0 + fl;
        float bv = (gf < Nout) ? bias[gf] : 0.f;
#pragma unroll
        for (int t = 0; t < 4; t++) {
            h4 pk;
#pragma unroll
            for (int rg = 0; rg < 4; rg++) pk[rg] = (_Float16)(acc[t][c][rg] + bv);
            *(h4*)&T[fl * TSS + 64 * w + 16 * t + q * 4] = pk;
        }
    }
    __syncthreads();

    // ---- stage 2: out = DAD @ T ----
    f32x4 acc2[CT][4];
#pragma unroll
    for (int f = 0; f < CT; f++)
#pragma unroll
        for (int t = 0; t < 4; t++) acc2[f][t] = (f32x4){0.f, 0.f, 0.f, 0.f};

    h8 b2[2][4];
#pragma unroll
    for (int t = 0; t < 4; t++)
        b2[0][t] = *(const h8*)(dadp + ((((4 * w + t) * 32 + q) * 16 + ln) << 3));

#pragma unroll
    for (int kb = 0; kb < 32; kb += 4) {
        const int cur = (kb >> 2) & 1, nxt = cur ^ 1;
        if (kb + 4 < 32) {
#pragma unroll
            for (int t = 0; t < 4; t++)
                b2[nxt][t] = *(const h8*)(dadp + ((((4 * w + t) * 32 + kb + 4 + q) * 16 + ln) << 3));
        }
        h8 a2[CT];
#pragma unroll
        for (int f = 0; f < CT; f++)
            a2[f] = *(const h8*)&T[(16 * f + ln) * TSS + (kb + q) * 8];
#pragma unroll
        for (int t = 0; t < 4; t++)
#pragma unroll
            for (int f = 0; f < CT; f++)
                acc2[f][t] = __builtin_amdgcn_mfma_f32_16x16x32_f16(a2[f], b2[cur][t], acc2[f][t], 0, 0, 0);
    }

    if constexpr (MODE == 0) {
        // relu; store into next layer's panel layout (512B-contiguous per store inst)
        const int KPBn = SN >> 3;
        f16* xn = Xn + (size_t)b * KPBn * 2048;
#pragma unroll
        for (int f = 0; f < CT; f++) {
            int fb = n0 + 16 * f + q * 4;
            if (fb >= SN) continue;
            int fb8 = fb >> 3, off = fb & 7;
#pragma unroll
            for (int t = 0; t < 4; t++) {
                h4 pk;
#pragma unroll
                for (int rg = 0; rg < 4; rg++) pk[rg] = (_Float16)fmaxf(acc2[f][t][rg], 0.f);
                *(h4*)(xn + ((((size_t)(4 * w + t) * KPBn + fb8) * 16 + ln) << 3) + off) = pk;
            }
        }
    } else {
        // MODE 2 (L4): T5[b][node][j] += sum_feat relu(acc2)*W5[feat][j]
        float s0[4], s1[4];
#pragma unroll
        for (int t = 0; t < 4; t++) { s0[t] = 0.f; s1[t] = 0.f; }
#pragma unroll
        for (int f = 0; f < CT; f++) {
#pragma unroll
            for (int rg = 0; rg < 4; rg++) {
                int feat = n0 + 16 * f + q * 4 + rg;
                float w50 = 0.f, w51 = 0.f;
                if (feat < 400) { w50 = W5g[feat * 2]; w51 = W5g[feat * 2 + 1]; }
#pragma unroll
                for (int t = 0; t < 4; t++) {
                    float v = fmaxf(acc2[f][t][rg], 0.f);
                    s0[t] += v * w50;
                    s1[t] += v * w51;
                }
            }
        }
#pragma unroll
        for (int t = 0; t < 4; t++) {
            s0[t] += __shfl_xor(s0[t], 16); s0[t] += __shfl_xor(s0[t], 32);
            s1[t] += __shfl_xor(s1[t], 16); s1[t] += __shfl_xor(s1[t], 32);
        }
        if (q == 0) {
#pragma unroll
            for (int t = 0; t < 4; t++) {
                int node = 64 * w + 16 * t + ln;
                atomicAdd(&T5[((size_t)b * 256 + node) * 2 + 0], s0[t]);
                atomicAdd(&T5[((size_t)b * 256 + node) * 2 + 1], s1[t]);
            }
        }
    }
}

// ========== final: out[b][i][0:2] = relu( DADsp @ T5[b] + rsp[i]*b5 ) ==========
__global__ __launch_bounds__(256) void dad_out(
        const float* __restrict__ dadsp, const float* __restrict__ T5,
        const float* __restrict__ rsp, const float* __restrict__ b5,
        float* __restrict__ out) {
    int gw = blockIdx.x * 4 + (threadIdx.x >> 6);
    int lane = threadIdx.x & 63;
    int b = gw >> 8, i = gw & 255;
    if (i >= NN) return;
    f32x4 d = ((const f32x4*)(dadsp + (size_t)i * 256))[lane];
    const float4* t5 = (const float4*)(T5 + (size_t)b * 512);
    float4 f0 = t5[2 * lane], f1 = t5[2 * lane + 1];
    float a0 = d.x * f0.x + d.y * f0.z + d.z * f1.x + d.w * f1.z;
    float a1 = d.x * f0.y + d.y * f0.w + d.z * f1.y + d.w * f1.w;
#pragma unroll
    for (int off = 1; off < 64; off <<= 1) {
        a0 += __shfl_xor(a0, off);
        a1 += __shfl_xor(a1, off);
    }
    if (lane == 0) {
        float rv = rsp[i];
        float2 v;
        v.x = fmaxf(a0 + rv * b5[0], 0.f);
        v.y = fmaxf(a1 + rv * b5[1], 0.f);
        *(float2*)(out + ((size_t)b * NN + i) * 2) = v;
    }
}

// ---------------- launcher ----------------

extern "C" void kernel_launch(void* const* d_in, const int* in_sizes, int n_in,
                              void* d_out, int out_size, void* d_ws, size_t ws_size,
                              hipStream_t stream) {
    const float* H   = (const float*)d_in[0];
    const float* W[6]  = {(const float*)d_in[3], (const float*)d_in[5], (const float*)d_in[7],
                          (const float*)d_in[9], (const float*)d_in[11], (const float*)d_in[13]};
    const float* Bv[6] = {(const float*)d_in[4], (const float*)d_in[6], (const float*)d_in[8],
                          (const float*)d_in[10], (const float*)d_in[12], (const float*)d_in[14]};
    const int* smi = (const int*)d_in[15];
    const int* spi = (const int*)d_in[16];

    char* p = (char*)d_ws;
    f16* bufA = (f16*)p;            p += 109051904;   // X2 panels
    f16* bufB = (f16*)p;            p += 83886080;    // X1/X3 panels [b*16+nt][40][16][8]
    float* dadsm = (float*)p;       p += 261120;      // [255][256] f32
    float* dadsp = (float*)p;       p += 261120;      // contiguous after dadsm
    f16* dadpsm = (f16*)p;          p += 131072;      // [16][32][16][8] f16 panels
    f16* dadpsp = (f16*)p;          p += 131072;      // contiguous after dadpsm
    f16* Wt1 = (f16*)p;             p += 266240;      // [20][52][16][8] (19 used)
    f16* Wt2 = (f16*)p;             p += 81920;       // [8][40][16][8]
    f16* Wt3 = (f16*)p;             p += 81920;       // [20][16][16][8]
    f16* Wt4 = (f16*)p;             p += 286720;      // [28][40][16][8]
    float* T0f = (float*)p;         p += 1048576;     // [512][256][2] f32
    float* T5  = (float*)p;         p += 1048576;     // [512][256][2] f32
    float* rsm = (float*)p;         p += 1024;
    float* rsp = (float*)p;         p += 1024;

    // zero via memset (graph-capturable), then 3 setup launches
    hipMemsetAsync(dadsm, 0, 522240, stream);          // dadsm + dadsp
    hipMemsetAsync(T5, 0, 1048576, stream);
    setup1<<<1216, 256, 0, stream>>>(W[1], W[2], W[3], W[4], Wt1, Wt2, Wt3, Wt4);
    setup2<<<20, 256, 0, stream>>>(smi, (const float*)d_in[1], spi, (const float*)d_in[2],
                                   dadsm, dadsp);
    setup3<<<33408, 256, 0, stream>>>(dadsm, dadpsm, rsm, rsp, H, T0f);

    // L0+L1 fused via rank-2 A-generation
    fused_layer<52, 4, true,  0><<<BB * 5, 256, 0, stream>>>(
        nullptr, Wt1, Bv[1], dadpsm, bufB, 300, 320, 5, 0,
        T0f, rsm, W[0], Bv[0], nullptr, nullptr);
    // L2 (300->100)
    fused_layer<40, 4, false, 0><<<BB * 2, 256, 0, stream>>>(
        bufB, Wt2, Bv[2], dadpsm, bufA, 100, 128, 2, 1,
        nullptr, nullptr, nullptr, nullptr, nullptr, nullptr);
    // L3 (100->300)
    fused_layer<16, 4, false, 0><<<BB * 5, 256, 0, stream>>>(
        bufA, Wt3, Bv[3], dadpsp, bufB, 300, 320, 5, 0,
        nullptr, nullptr, nullptr, nullptr, nullptr, nullptr);
    // L4 (300->400) + fused X4@W5 -> T5 atomics (X4 never stored)
    fused_layer<40, 4, false, 2><<<BB * 7, 256, 0, stream>>>(
        bufB, Wt4, Bv[4], dadpsp, nullptr, 400, 0, 7, 1,
        nullptr, nullptr, nullptr, nullptr, W[5], T5);
    // final: out = relu(DADsp @ T5 + rsp b5^T)
    dad_out<<<32768, 256, 0, stream>>>(dadsp, T5, rsp, Bv[5], (float*)d_out);
}

// Round 15
// 331.892 us; speedup vs baseline: 1.1501x; 1.1501x over previous
//
#include <hip/hip_runtime.h>
#include <hip/hip_fp16.h>

typedef __half f16;
typedef _Float16 h8 __attribute__((ext_vector_type(8)));
typedef _Float16 h4 __attribute__((ext_vector_type(4)));
typedef _Float16 h2 __attribute__((ext_vector_type(2)));
typedef float f32x4 __attribute__((ext_vector_type(4)));

#define NN 255          // real nodes
#define BB 512          // batch
#define TSS 264         // T LDS row stride in f16

static __device__ __forceinline__ f16 f2h(float x) { return __float2half(x); }

union H8u { h8 v; h2 p[4]; };

// ========== setup1: zero DADs + zero T5 + convert W1..W5 to k-panel f16 ==========
// NOTE (round-14 lesson): k-panel [k/8][256][8] keeps the four t-stream loads 256 B apart
// -> compiler folds them into one voffset + immediate offsets. 16-row panels broke that.
__device__ __forceinline__ void conv_wt(const float* __restrict__ W, f16* __restrict__ Wtp,
                                        int K, int N, int KPB, int f, int tid) {
    int tile = f >> 6, fl = f & 63;
    int Kpad = KPB * 8;
    for (int k = tid; k < Kpad; k += 256) {
        float v = (f < N && k < K) ? W[(size_t)k * N + f] : 0.f;
        Wtp[((((size_t)tile * KPB + (k >> 3)) * 64 + fl) << 3) + (k & 7)] = f2h(v);
    }
}

// grid MUST be 510 (dad zero) + 1024 (T5 zero) + 320+128+320+448+64 (weights) = 2814
__global__ __launch_bounds__(256) void setup1(
        float* __restrict__ dadsm, float* __restrict__ T5,
        const float* W1, const float* W2, const float* W3, const float* W4, const float* W5,
        f16* Wt1, f16* Wt2, f16* Wt3, f16* Wt4, f16* Wt5) {
    int bi = blockIdx.x, tid = threadIdx.x;
    if (bi < 510) { dadsm[bi * 256 + tid] = 0.f; return; }          // dadsm+dadsp contiguous
    if (bi < 1534) { T5[(bi - 510) * 256 + tid] = 0.f; return; }    // 262144 f32
    int f = bi - 1534;
    if (f < 320) conv_wt(W1, Wt1, 400, 300, 52, f, tid);
    else if (f < 448) conv_wt(W2, Wt2, 300, 100, 40, f - 320, tid);
    else if (f < 768) conv_wt(W3, Wt3, 100, 300, 16, f - 448, tid);
    else if (f < 1216) conv_wt(W4, Wt4, 300, 400, 40, f - 768, tid);
    else conv_wt(W5, Wt5, 400, 2, 52, f - 1216, tid);
}

// ========== setup2: scatter COO -> dense ==========
__global__ void setup2(const int* __restrict__ smi, const float* __restrict__ smv,
                       const int* __restrict__ spi, const float* __restrict__ spv,
                       float* __restrict__ dadsm, float* __restrict__ dadsp) {
    int t = blockIdx.x * 256 + threadIdx.x;
    if (blockIdx.x < 10) {
        if (t < 2550) atomicAdd(&dadsm[smi[2 * t] * 256 + smi[2 * t + 1]], smv[t]);
    } else {
        t -= 2560;
        if (t >= 0 && t < 2550) atomicAdd(&dadsp[spi[2 * t] * 256 + spi[2 * t + 1]], spv[t]);
    }
}

// ========== setup3: DAD k-panel f16 + rowsums (rsm, rsp) + T0f = DADsm@H ==========
// grid = 512 + 64 + 64 + 32768 = 33408
__global__ __launch_bounds__(256) void setup3(
        const float* __restrict__ dadsm, f16* __restrict__ dadpsm,
        float* __restrict__ rsm, float* __restrict__ rsp,
        const float* __restrict__ H, float* __restrict__ T0f) {
    int bi = blockIdx.x, tid = threadIdx.x;
    if (bi < 512) {                        // convert both DADs (dadpsp contiguous after dadpsm)
        int i = bi * 256 + tid;
        int which = i >> 16, rc = i & 65535;
        int node = rc >> 8, k = rc & 255;
        float v = (node < NN) ? dadsm[(size_t)which * NN * 256 + rc] : 0.f;
        dadpsm[(size_t)which * 65536 + (((k >> 3) * 256 + node) << 3) + (k & 7)] = f2h(v);
        return;
    }
    int lane = tid & 63;
    if (bi < 640) {                        // rowsums: 512..575 rsm, 576..639 rsp
        int which = (bi < 576) ? 0 : 1;
        int base = which ? 576 : 512;
        const float* dm = dadsm + (size_t)which * NN * 256;
        float* r = which ? rsp : rsm;
        int i = (bi - base) * 4 + (tid >> 6);
        float s = 0.f;
        if (i < NN) {
            f32x4 d = ((const f32x4*)(dm + (size_t)i * 256))[lane];
            s = d.x + d.y + d.z + d.w;
#pragma unroll
            for (int off = 1; off < 64; off <<= 1) s += __shfl_xor(s, off);
        }
        if (lane == 0 && i < 256) r[i] = (i < NN) ? s : 0.f;
        return;
    }
    // T0f[b][node][2] = (DADsm @ H): wave per (b,node)
    int gw = (bi - 640) * 4 + (tid >> 6);
    if (gw >= BB * 256) return;
    int b = gw >> 8, i = gw & 255;
    float a0 = 0.f, a1 = 0.f;
    if (i < NN) {
        f32x4 d = ((const f32x4*)(dadsm + (size_t)i * 256))[lane];
        const float2* yb2 = (const float2*)(H + (size_t)b * 510);
        float2 p0 = yb2[4 * lane], p1 = yb2[4 * lane + 1], p2 = yb2[4 * lane + 2];
        float2 p3 = (lane < 63) ? yb2[4 * lane + 3] : make_float2(0.f, 0.f);
        a0 = d.x * p0.x + d.y * p1.x + d.z * p2.x + d.w * p3.x;
        a1 = d.x * p0.y + d.y * p1.y + d.z * p2.y + d.w * p3.y;
#pragma unroll
        for (int off = 1; off < 64; off <<= 1) {
            a0 += __shfl_xor(a0, off);
            a1 += __shfl_xor(a1, off);
        }
    }
    if (lane == 0) {
        T0f[(size_t)gw * 2 + 0] = a0;
        T0f[(size_t)gw * 2 + 1] = a1;
    }
}

// ============ fused layer: Xn = relu( DAD @ (X@W + bias) ) ============
// MODE 0: store f16 k-panel. MODE 2 (L4): no store; contract relu(acc2) with W5 in-register
// and atomicAdd f32 partials into T5[b][node][2] (X4 never touches HBM).
// R2 (L1): A-fragments generated in-register as relu(rank-2 L0 expansion) — no X reads.
template <int KPB, int CT, bool R2, int MODE>
__global__ __launch_bounds__(256, 4) void fused_layer(
        const f16* __restrict__ X,      // [512][KPB][256][8] zero-padded (unused if R2)
        const f16* __restrict__ Wtp,    // [ntiles][KPB][64][8] zero-padded
        const float* __restrict__ bias, // [Nout] f32
        const f16* __restrict__ dadp,   // [32][256][8]
        f16* __restrict__ Xn,           // MODE 0: [512][SN/8][256][8]
        int Nout, int SN, int ntiles, int rev,
        const float* __restrict__ T0p,  // R2: [512][256][2] f32
        const float* __restrict__ rsmp, // R2: [256] f32
        const float* __restrict__ W0f,  // R2: [2][400] f32
        const float* __restrict__ b0f,  // R2: [400] f32
        const float* __restrict__ W5g,  // MODE 2: [400][2] f32
        float* __restrict__ T5) {       // MODE 2: [512][256][2] f32 (pre-zeroed)
    __shared__ _Float16 T[64 * TSS];
    __shared__ _Float16 WL[R2 ? 1344 : 4];
    const int id = blockIdx.x;
    int s = id >> 3;
    int bq = s / ntiles;
    const int tile = s - bq * ntiles;
    if (rev) bq = 63 - bq;
    const int b = ((id & 7) << 6) + bq;
    const int n0 = tile * 64;
    const int tid = threadIdx.x;
    const int w = tid >> 6;
    const int ln = tid & 15;
    const int q = (tid >> 4) & 3;

    // ---- R2 prologue ----
    h2 a0s[4], a1s[4], rvs[4];
    if constexpr (R2) {
        for (int i2 = tid; i2 < 448; i2 += 256) {
            WL[i2]       = (_Float16)(i2 < 400 ? W0f[i2] : 0.f);
            WL[448 + i2] = (_Float16)(i2 < 400 ? W0f[400 + i2] : 0.f);
            WL[896 + i2] = (_Float16)(i2 < 400 ? b0f[i2] : 0.f);
        }
#pragma unroll
        for (int t = 0; t < 4; t++) {
            int node = 64 * w + 16 * t + ln;
            const float* tp = T0p + ((size_t)b * 256 + node) * 2;
            _Float16 x0 = (_Float16)tp[0];
            _Float16 x1 = (_Float16)tp[1];
            _Float16 rv = (_Float16)rsmp[node];
            a0s[t] = (h2){x0, x0};
            a1s[t] = (h2){x1, x1};
            rvs[t] = (h2){rv, rv};
        }
        __syncthreads();
    }

    // ---- stage 1: wave w: nodes 64w..64w+63 x CT*16 feats ----
    f32x4 acc[4][CT];
#pragma unroll
    for (int t = 0; t < 4; t++)
#pragma unroll
        for (int c = 0; c < CT; c++) acc[t][c] = (f32x4){0.f, 0.f, 0.f, 0.f};

    const f16* xb = R2 ? (const f16*)nullptr : X + (size_t)b * KPB * 2048;
    const f16* wp = Wtp + (size_t)tile * KPB * 512;

    h8 afr[2][4];
    if constexpr (!R2) {
#pragma unroll
        for (int t = 0; t < 4; t++)
            afr[0][t] = *(const h8*)(xb + ((q * 256 + 64 * w + 16 * t + ln) << 3));
    }

#pragma unroll
    for (int kb = 0; kb < KPB; kb += 4) {
        const int cur = (kb >> 2) & 1, nxt = cur ^ 1;
        h8 bf[CT];
#pragma unroll
        for (int c = 0; c < CT; c++)
            bf[c] = *(const h8*)(wp + (((kb + q) * 64 + 16 * c + ln) << 3));
        h8 afc[4];
        if constexpr (R2) {
            H8u wa, wb, bl;
            wa.v = *(const h8*)&WL[(kb + q) * 8];
            wb.v = *(const h8*)&WL[448 + (kb + q) * 8];
            bl.v = *(const h8*)&WL[896 + (kb + q) * 8];
            const h2 z2 = (h2){(_Float16)0.f, (_Float16)0.f};
#pragma unroll
            for (int t = 0; t < 4; t++) {
                H8u r;
#pragma unroll
                for (int j = 0; j < 4; j++)
                    r.p[j] = __builtin_elementwise_max(
                        a0s[t] * wa.p[j] + a1s[t] * wb.p[j] + rvs[t] * bl.p[j], z2);
                afc[t] = r.v;
            }
        } else {
            if (kb + 4 < KPB) {
#pragma unroll
                for (int t = 0; t < 4; t++)
                    afr[nxt][t] = *(const h8*)(xb + (((kb + 4 + q) * 256 + 64 * w + 16 * t + ln) << 3));
            }
#pragma unroll
            for (int t = 0; t < 4; t++) afc[t] = afr[cur][t];
        }
#pragma unroll
        for (int c = 0; c < CT; c++)
#pragma unroll
            for (int t = 0; t < 4; t++)
                acc[t][c] = __builtin_amdgcn_mfma_f32_16x16x32_f16(afc[t], bf[c], acc[t][c], 0, 0, 0);
    }

    // bias + pack to T[feat][node]
#pragma unroll
    for (int c = 0; c < CT; c++) {
        int fl = 16 * c + ln;
        int gf = n0 + fl;
        float bv = (gf < Nout) ? bias[gf] : 0.f;
#pragma unroll
        for (int t = 0; t < 4; t++) {
            h4 pk;
#pragma unroll
            for (int rg = 0; rg < 4; rg++) pk[rg] = (_Float16)(acc[t][c][rg] + bv);
            *(h4*)&T[fl * TSS + 64 * w + 16 * t + q * 4] = pk;
        }
    }
    __syncthreads();

    // ---- stage 2: out = DAD @ T ----
    f32x4 acc2[CT][4];
#pragma unroll
    for (int f = 0; f < CT; f++)
#pragma unroll
        for (int t = 0; t < 4; t++) acc2[f][t] = (f32x4){0.f, 0.f, 0.f, 0.f};

    h8 b2[2][4];
#pragma unroll
    for (int t = 0; t < 4; t++)
        b2[0][t] = *(const h8*)(dadp + ((q * 256 + 64 * w + 16 * t + ln) << 3));

#pragma unroll
    for (int kb = 0; kb < 32; kb += 4) {
        const int cur = (kb >> 2) & 1, nxt = cur ^ 1;
        if (kb + 4 < 32) {
#pragma unroll
            for (int t = 0; t < 4; t++)
                b2[nxt][t] = *(const h8*)(dadp + (((kb + 4 + q) * 256 + 64 * w + 16 * t + ln) << 3));
        }
        h8 a2[CT];
#pragma unroll
        for (int f = 0; f < CT; f++)
            a2[f] = *(const h8*)&T[(16 * f + ln) * TSS + (kb + q) * 8];
#pragma unroll
        for (int t = 0; t < 4; t++)
#pragma unroll
            for (int f = 0; f < CT; f++)
                acc2[f][t] = __builtin_amdgcn_mfma_f32_16x16x32_f16(a2[f], b2[cur][t], acc2[f][t], 0, 0, 0);
    }

    if constexpr (MODE == 0) {
        // relu; store into next layer's k-panel layout
        f16* xn = Xn + (size_t)b * (SN >> 3) * 2048;
#pragma unroll
        for (int f = 0; f < CT; f++) {
            int fb = n0 + 16 * f + q * 4;
            if (fb >= SN) continue;
            int fb8 = fb >> 3, off = fb & 7;
#pragma unroll
            for (int t = 0; t < 4; t++) {
                int node = 64 * w + 16 * t + ln;
                h4 pk;
#pragma unroll
                for (int rg = 0; rg < 4; rg++) pk[rg] = (_Float16)fmaxf(acc2[f][t][rg], 0.f);
                *(h4*)(xn + (((size_t)fb8 * 256 + node) << 3) + off) = pk;
            }
        }
    } else {
        // MODE 2 (L4): T5[b][node][j] += sum_feat relu(acc2)*W5[feat][j]
        float s0[4], s1[4];
#pragma unroll
        for (int t = 0; t < 4; t++) { s0[t] = 0.f; s1[t] = 0.f; }
#pragma unroll
        for (int f = 0; f < CT; f++) {
#pragma unroll
            for (int rg = 0; rg < 4; rg++) {
                int feat = n0 + 16 * f + q * 4 + rg;
                float w50 = 0.f, w51 = 0.f;
                if (feat < 400) { w50 = W5g[feat * 2]; w51 = W5g[feat * 2 + 1]; }
#pragma unroll
                for (int t = 0; t < 4; t++) {
                    float v = fmaxf(acc2[f][t][rg], 0.f);
                    s0[t] += v * w50;
                    s1[t] += v * w51;
                }
            }
        }
#pragma unroll
        for (int t = 0; t < 4; t++) {
            s0[t] += __shfl_xor(s0[t], 16); s0[t] += __shfl_xor(s0[t], 32);
            s1[t] += __shfl_xor(s1[t], 16); s1[t] += __shfl_xor(s1[t], 32);
        }
        if (q == 0) {
#pragma unroll
            for (int t = 0; t < 4; t++) {
                int node = 64 * w + 16 * t + ln;
                atomicAdd(&T5[((size_t)b * 256 + node) * 2 + 0], s0[t]);
                atomicAdd(&T5[((size_t)b * 256 + node) * 2 + 1], s1[t]);
            }
        }
    }
}

// ========== final: out[b][i][0:2] = relu( DADsp @ T5[b] + rsp[i]*b5 ) ==========
// grid 32768 blocks, wave per (b,i).
__global__ __launch_bounds__(256) void dad_out(
        const float* __restrict__ dadsp, const float* __restrict__ T5,
        const float* __restrict__ rsp, const float* __restrict__ b5,
        float* __restrict__ out) {
    int gw = blockIdx.x * 4 + (threadIdx.x >> 6);
    int lane = threadIdx.x & 63;
    int b = gw >> 8, i = gw & 255;
    if (i >= NN) return;
    f32x4 d = ((const f32x4*)(dadsp + (size_t)i * 256))[lane];
    const float4* t5 = (const float4*)(T5 + (size_t)b * 512);
    float4 f0 = t5[2 * lane], f1 = t5[2 * lane + 1];
    float a0 = d.x * f0.x + d.y * f0.z + d.z * f1.x + d.w * f1.z;
    float a1 = d.x * f0.y + d.y * f0.w + d.z * f1.y + d.w * f1.w;
#pragma unroll
    for (int off = 1; off < 64; off <<= 1) {
        a0 += __shfl_xor(a0, off);
        a1 += __shfl_xor(a1, off);
    }
    if (lane == 0) {
        float rv = rsp[i];
        float2 v;
        v.x = fmaxf(a0 + rv * b5[0], 0.f);
        v.y = fmaxf(a1 + rv * b5[1], 0.f);
        *(float2*)(out + ((size_t)b * NN + i) * 2) = v;
    }
}

// ---------------- launcher ----------------

extern "C" void kernel_launch(void* const* d_in, const int* in_sizes, int n_in,
                              void* d_out, int out_size, void* d_ws, size_t ws_size,
                              hipStream_t stream) {
    const float* H   = (const float*)d_in[0];
    const float* W[6]  = {(const float*)d_in[3], (const float*)d_in[5], (const float*)d_in[7],
                          (const float*)d_in[9], (const float*)d_in[11], (const float*)d_in[13]};
    const float* Bv[6] = {(const float*)d_in[4], (const float*)d_in[6], (const float*)d_in[8],
                          (const float*)d_in[10], (const float*)d_in[12], (const float*)d_in[14]};
    const int* smi = (const int*)d_in[15];
    const int* spi = (const int*)d_in[16];

    char* p = (char*)d_ws;
    f16* bufA = (f16*)p;            p += 109051904;   // X2 [512][16][256][8]
    f16* bufB = (f16*)p;            p += 83886080;    // X1/X3 [512][40][256][8]
    float* dadsm = (float*)p;       p += 261120;      // [255][256] f32
    float* dadsp = (float*)p;       p += 261120;
    f16* dadpsm = (f16*)p;          p += 131072;      // [32][256][8] f16 k-panel
    f16* dadpsp = (f16*)p;          p += 131072;      // contiguous after dadpsm
    f16* Wt1 = (f16*)p;             p += 266240;      // [5][52][64][8]
    f16* Wt2 = (f16*)p;             p += 81920;       // [2][40][64][8]
    f16* Wt3 = (f16*)p;             p += 81920;       // [5][16][64][8]
    f16* Wt4 = (f16*)p;             p += 286720;      // [7][40][64][8]
    f16* Wt5 = (f16*)p;             p += 53248;       // [1][52][64][8]
    float* T0f = (float*)p;         p += 1048576;     // [512][256][2] f32
    float* T5  = (float*)p;         p += 1048576;     // [512][256][2] f32
    float* rsm = (float*)p;         p += 1024;
    float* rsp = (float*)p;         p += 1024;

    // setup: 3 launches (grids: 510+1024+1280 = 2814 | 20 | 512+64+64+32768 = 33408)
    setup1<<<2814, 256, 0, stream>>>(dadsm, T5, W[1], W[2], W[3], W[4], W[5],
                                     Wt1, Wt2, Wt3, Wt4, Wt5);
    setup2<<<20, 256, 0, stream>>>(smi, (const float*)d_in[1], spi, (const float*)d_in[2],
                                   dadsm, dadsp);
    setup3<<<33408, 256, 0, stream>>>(dadsm, dadpsm, rsm, rsp, H, T0f);

    // L0+L1 fused via rank-2 A-generation: X1 = relu(DADsm @ (relu((DADsm H)W0 + r b0) W1 + b1))
    fused_layer<52, 4, true,  0><<<BB * 5, 256, 0, stream>>>(
        nullptr, Wt1, Bv[1], dadpsm, bufB, 300, 320, 5, 0,
        T0f, rsm, W[0], Bv[0], nullptr, nullptr);
    // L2 (300->100)
    fused_layer<40, 4, false, 0><<<BB * 2, 256, 0, stream>>>(
        bufB, Wt2, Bv[2], dadpsm, bufA, 100, 128, 2, 1,
        nullptr, nullptr, nullptr, nullptr, nullptr, nullptr);
    // L3 (100->300)
    fused_layer<16, 4, false, 0><<<BB * 5, 256, 0, stream>>>(
        bufA, Wt3, Bv[3], dadpsp, bufB, 300, 320, 5, 0,
        nullptr, nullptr, nullptr, nullptr, nullptr, nullptr);
    // L4 (300->400) + fused X4@W5 -> T5 atomics (X4 never stored)
    fused_layer<40, 4, false, 2><<<BB * 7, 256, 0, stream>>>(
        bufB, Wt4, Bv[4], dadpsp, nullptr, 400, 0, 7, 1,
        nullptr, nullptr, nullptr, nullptr, W[5], T5);
    // final: out = relu(DADsp @ T5 + rsp b5^T)
    dad_out<<<32768, 256, 0, stream>>>(dadsp, T5, rsp, Bv[5], (float*)d_out);
}